// Round 19
// baseline (38.842 us; speedup 1.0000x reference)
//
#include <hip/hip_runtime.h>
#include <math.h>

#define NROW 1024
#define BATCH 4
#define NT 16
#define NTRI 136             // 16*17/2
#define NPROD 512
#define PROD_ROWS 8
#define NROWS_TOT 4096
#define NPAIRBLK (BATCH * NTRI * 4)  // 2176: 4 J-quarters per tile pair (r15 best)

__device__ __forceinline__ float tanh_fast(float x) {
    const float e = __expf(2.f * fabsf(x));
    const float r = 1.f - 2.f / (e + 1.f);
    return copysignf(r, x);
}

// ---------------------------------------------------------------------------
// Dispatch A: feature producer (verbatim round-15). 512 x 256, 8 rows/block.
// ---------------------------------------------------------------------------
__global__ __launch_bounds__(256) void k_feat(
    const float* __restrict__ emb,   // [4096][128]
    const float* __restrict__ temp,  // [4096][64]
    const float* __restrict__ W1,    // [192][64]
    const float* __restrict__ b1,    // [64]
    const float* __restrict__ W2,    // [64][32]
    const float* __restrict__ b2,    // [32]
    const float* __restrict__ W3,    // [64][32]
    const float* __restrict__ b3,    // [32]
    float* __restrict__ hiS,         // [4096][32]
    float* __restrict__ hjbS)        // [4096][32]
{
    __shared__ __align__(16) float X[8 * 192];
    __shared__ __align__(16) float H[8 * 64];
    __shared__ __align__(16) float P[8 * 32];

    const int t = threadIdx.x;
    const int rowbase = blockIdx.x * PROD_ROWS;

    {
        const int idx0 = t;            // 0..255
        const int r0s = idx0 / 48, c0 = idx0 - r0s * 48;
        float4 v;
        if (c0 < 32) v = reinterpret_cast<const float4*>(emb)[(size_t)(rowbase + r0s) * 32 + c0];
        else         v = reinterpret_cast<const float4*>(temp)[(size_t)(rowbase + r0s) * 16 + (c0 - 32)];
        *reinterpret_cast<float4*>(&X[r0s * 192 + c0 * 4]) = v;
        if (t < 128) {
            const int idx1 = t + 256;  // 256..383
            const int r1s = idx1 / 48, c1 = idx1 - r1s * 48;
            float4 v1;
            if (c1 < 32) v1 = reinterpret_cast<const float4*>(emb)[(size_t)(rowbase + r1s) * 32 + c1];
            else         v1 = reinterpret_cast<const float4*>(temp)[(size_t)(rowbase + r1s) * 16 + (c1 - 32)];
            *reinterpret_cast<float4*>(&X[r1s * 192 + c1 * 4]) = v1;
        }
    }
    __syncthreads();

    // L1: [8x192]@[192x64]+b1 -> relu -> H (2 independent rows/thread)
    {
        const int o = t & 63;
        const int r0 = t >> 6;  // 0..3 -> rows r0, r0+4
        float s0 = b1[o], s1 = s0;
#pragma unroll 4
        for (int k4 = 0; k4 < 48; ++k4) {
            const float4 x0 = *reinterpret_cast<const float4*>(&X[r0 * 192 + k4 * 4]);
            const float4 x1 = *reinterpret_cast<const float4*>(&X[(r0 + 4) * 192 + k4 * 4]);
            const float w0 = W1[(k4 * 4 + 0) * 64 + o];
            const float w1 = W1[(k4 * 4 + 1) * 64 + o];
            const float w2 = W1[(k4 * 4 + 2) * 64 + o];
            const float w3 = W1[(k4 * 4 + 3) * 64 + o];
            s0 = fmaf(x0.w, w3, fmaf(x0.z, w2, fmaf(x0.y, w1, fmaf(x0.x, w0, s0))));
            s1 = fmaf(x1.w, w3, fmaf(x1.z, w2, fmaf(x1.y, w1, fmaf(x1.x, w0, s1))));
        }
        H[r0 * 64 + o]       = fmaxf(s0, 0.f);
        H[(r0 + 4) * 64 + o] = fmaxf(s1, 0.f);
    }
    __syncthreads();

    // L2: [8x64]@[64x32]+b2 -> relu -> P (1 row/thread)
    {
        const int o2 = t & 31;
        const int r8 = t >> 5;  // 0..7
        float s = b2[o2];
#pragma unroll 8
        for (int k = 0; k < 64; ++k) s += H[r8 * 64 + k] * W2[k * 32 + o2];
        P[r8 * 32 + o2] = fmaxf(s, 0.f);
    }
    __syncthreads();

    // L3: hi = P@W3[:32]; hjb = P@W3[32:]+b3 (1 row/thread)
    {
        const int o2 = t & 31;
        const int r8 = t >> 5;
        float sa = 0.f, sb = b3[o2];
#pragma unroll 8
        for (int k = 0; k < 32; ++k) {
            const float p = P[r8 * 32 + k];
            sa += p * W3[k * 32 + o2];
            sb += p * W3[(32 + k) * 32 + o2];
        }
        hiS[(size_t)(rowbase + r8) * 32 + o2] = sa;
        hjbS[(size_t)(rowbase + r8) * 32 + o2] = sb;
    }
}

// ---------------------------------------------------------------------------
// Dispatch B: pairwise consumer — r15 geometry, J-operands REGISTERIZED
// (loaded once from global; k-loop does only 2 LDS reads/k instead of 4).
// 2176 blocks x 256 threads, per-thread 4x1 both directions.
// ---------------------------------------------------------------------------
__global__ __launch_bounds__(256) void k_pair(
    const float* __restrict__ hiS,   // [4096][32]
    const float* __restrict__ hjbS,  // [4096][32]
    const float* __restrict__ W4,    // [32]
    const float* __restrict__ b4,    // [1]
    float* __restrict__ out)         // [4][1024][1024]
{
    __shared__ __align__(16) float AiT[32 * 68];  // hi  I rows, [k][r0..63]
    __shared__ __align__(16) float BiT[32 * 68];  // hjb I rows

    const int t = threadIdx.x;
    const int bx = blockIdx.x;
    const int pb = bx >> 2;      // tile-pair index
    const int q = bx & 3;        // J quarter: cols [q*16, q*16+16)
    const int b = pb / NTRI;
    int tidx = pb % NTRI;
    int ti = 0;
    while (tidx >= NT - ti) { tidx -= NT - ti; ++ti; }
    const int tj = ti + tidx;

    const float* hiB  = hiS + (size_t)b * (NROW * 32);
    const float* hjbB = hjbS + (size_t)b * (NROW * 32);

    const int ty = t >> 4;  // 0..15 -> 4 I-rows (i0..i0+3)
    const int tx = t & 15;  // 0..15 -> 1 J-col

    // ---- J-operands to registers: 32 hi + 32 hjb floats (static indexing) ----
    const int jrow = tj * 64 + q * 16 + tx;
    float ajr[32], bjr[32];
    {
        const float4* ajp = reinterpret_cast<const float4*>(hiB + (size_t)jrow * 32);
        const float4* bjp = reinterpret_cast<const float4*>(hjbB + (size_t)jrow * 32);
#pragma unroll
        for (int k4 = 0; k4 < 8; ++k4) {
            const float4 va = ajp[k4];
            const float4 vb = bjp[k4];
            ajr[4 * k4 + 0] = va.x; ajr[4 * k4 + 1] = va.y;
            ajr[4 * k4 + 2] = va.z; ajr[4 * k4 + 3] = va.w;
            bjr[4 * k4 + 0] = vb.x; bjr[4 * k4 + 1] = vb.y;
            bjr[4 * k4 + 2] = vb.z; bjr[4 * k4 + 3] = vb.w;
        }
    }

    // ---- stage I tiles (full 64 rows), proven path ----
#pragma unroll
    for (int rep = 0; rep < 2; ++rep) {
        const int idx = t + rep * 256;  // 0..511
        const int r = idx >> 3, k4 = idx & 7;
        const float4 vhi = reinterpret_cast<const float4*>(hiB)[(ti * 64 + r) * 8 + k4];
        const float4 vhj = reinterpret_cast<const float4*>(hjbB)[(ti * 64 + r) * 8 + k4];
        AiT[(k4 * 4 + 0) * 68 + r] = vhi.x; AiT[(k4 * 4 + 1) * 68 + r] = vhi.y;
        AiT[(k4 * 4 + 2) * 68 + r] = vhi.z; AiT[(k4 * 4 + 3) * 68 + r] = vhi.w;
        BiT[(k4 * 4 + 0) * 68 + r] = vhj.x; BiT[(k4 * 4 + 1) * 68 + r] = vhj.y;
        BiT[(k4 * 4 + 2) * 68 + r] = vhj.z; BiT[(k4 * 4 + 3) * 68 + r] = vhj.w;
    }
    __syncthreads();

    float F[4] = {};  // z(i0+a, j0)
    float G[4] = {};  // z(j0, i0+a)
#pragma unroll
    for (int k = 0; k < 32; ++k) {
        const float w = W4[k];
        const float4 ai = *reinterpret_cast<const float4*>(&AiT[k * 68 + 4 * ty]);  // hi  I
        const float4 bi = *reinterpret_cast<const float4*>(&BiT[k * 68 + 4 * ty]);  // hjb I
        const float aj = ajr[k];  // hi  J (register)
        const float bj = bjr[k];  // hjb J (register)
        const float av[4] = {ai.x, ai.y, ai.z, ai.w};
        const float bw[4] = {bi.x, bi.y, bi.z, bi.w};
#pragma unroll
        for (int a = 0; a < 4; ++a) {
            F[a] = fmaf(fmaxf(av[a] + bj, 0.f), w, F[a]);
            G[a] = fmaf(fmaxf(aj + bw[a], 0.f), w, G[a]);
        }
    }

    const float bb = *b4;
    float S[4];
#pragma unroll
    for (int a = 0; a < 4; ++a)
        S[a] = 0.5f * (tanh_fast(F[a] + bb) + tanh_fast(G[a] + bb));

    float* outb = out + (size_t)b * (NROW * NROW);
    const int i0 = ti * 64 + 4 * ty;
    const int j0 = jrow;
#pragma unroll
    for (int a = 0; a < 4; ++a)
        outb[(size_t)(i0 + a) * NROW + j0] = S[a];
    if (ti != tj) {
        float4 v = make_float4(S[0], S[1], S[2], S[3]);
        *reinterpret_cast<float4*>(&outb[(size_t)j0 * NROW + i0]) = v;
    }
}

// ---------------------------------------------------------------------------
// Fallback (ws too small): round-4 self-contained kernel, known-good @229us.
// ---------------------------------------------------------------------------
__global__ __launch_bounds__(256) void fused_fallback(
    const float* __restrict__ emb, const float* __restrict__ temp,
    const float* __restrict__ W1, const float* __restrict__ b1,
    const float* __restrict__ W2, const float* __restrict__ b2,
    const float* __restrict__ W3, const float* __restrict__ b3,
    const float* __restrict__ W4, const float* __restrict__ b4,
    float* __restrict__ out)
{
    __shared__ __align__(16) float FT[4][32][68];
    __shared__ __align__(16) float X[16][192];
    __shared__ __align__(16) float H[16][64];
    __shared__ __align__(16) float P[16][32];

    const int t = threadIdx.x;
    const int bx = blockIdx.x;
    const int b = bx / NTRI;
    int tidx = bx % NTRI;
    int ti = 0;
    while (tidx >= NT - ti) { tidx -= NT - ti; ++ti; }
    const int tj = ti + tidx;

    for (int ch = 0; ch < 8; ++ch) {
        const int tile = (ch < 4) ? ti : tj;
        const int sub = ch & 3;
        const int half = ch >> 2;
        const int rowbase = b * NROW + tile * 64 + sub * 16;
#pragma unroll
        for (int rep = 0; rep < 3; ++rep) {
            const int idx = t + rep * 256;
            const int r = idx / 48;
            const int c = idx - r * 48;
            float4 v;
            if (c < 32) v = reinterpret_cast<const float4*>(emb)[(size_t)(rowbase + r) * 32 + c];
            else        v = reinterpret_cast<const float4*>(temp)[(size_t)(rowbase + r) * 16 + (c - 32)];
            *reinterpret_cast<float4*>(&X[r][c * 4]) = v;
        }
        __syncthreads();
        {
            const int o = t & 63;
            const int r0 = t >> 6;
            float s0 = b1[o], s1 = s0, s2 = s0, s3 = s0;
#pragma unroll 4
            for (int k4 = 0; k4 < 48; ++k4) {
                const float4 x0 = *reinterpret_cast<const float4*>(&X[r0][k4 * 4]);
                const float4 x1 = *reinterpret_cast<const float4*>(&X[r0 + 4][k4 * 4]);
                const float4 x2 = *reinterpret_cast<const float4*>(&X[r0 + 8][k4 * 4]);
                const float4 x3 = *reinterpret_cast<const float4*>(&X[r0 + 12][k4 * 4]);
                const float w0 = W1[(k4 * 4 + 0) * 64 + o];
                const float w1 = W1[(k4 * 4 + 1) * 64 + o];
                const float w2 = W1[(k4 * 4 + 2) * 64 + o];
                const float w3 = W1[(k4 * 4 + 3) * 64 + o];
                s0 = fmaf(x0.w, w3, fmaf(x0.z, w2, fmaf(x0.y, w1, fmaf(x0.x, w0, s0))));
                s1 = fmaf(x1.w, w3, fmaf(x1.z, w2, fmaf(x1.y, w1, fmaf(x1.x, w0, s1))));
                s2 = fmaf(x2.w, w3, fmaf(x2.z, w2, fmaf(x2.y, w1, fmaf(x2.x, w0, s2))));
                s3 = fmaf(x3.w, w3, fmaf(x3.z, w2, fmaf(x3.y, w1, fmaf(x3.x, w0, s3))));
            }
            H[r0][o] = fmaxf(s0, 0.f);
            H[r0 + 4][o] = fmaxf(s1, 0.f);
            H[r0 + 8][o] = fmaxf(s2, 0.f);
            H[r0 + 12][o] = fmaxf(s3, 0.f);
        }
        __syncthreads();
        {
            const int o2 = t & 31;
            const int r8 = t >> 5;
#pragma unroll
            for (int rr = 0; rr < 2; ++rr) {
                const int r = r8 + rr * 8;
                float s = b2[o2];
#pragma unroll 8
                for (int k = 0; k < 64; ++k) s += H[r][k] * W2[k * 32 + o2];
                P[r][o2] = fmaxf(s, 0.f);
            }
        }
        __syncthreads();
        {
            const int o2 = t & 31;
            const int r8 = t >> 5;
#pragma unroll
            for (int rr = 0; rr < 2; ++rr) {
                const int r = r8 + rr * 8;
                float sa = 0.f, sb = b3[o2];
#pragma unroll 8
                for (int k = 0; k < 32; ++k) {
                    const float p = P[r][k];
                    sa += p * W3[k * 32 + o2];
                    sb += p * W3[(32 + k) * 32 + o2];
                }
                FT[half * 2 + 0][o2][sub * 16 + r] = sa;
                FT[half * 2 + 1][o2][sub * 16 + r] = sb;
            }
        }
        __syncthreads();
    }

    const int ty = t >> 4;
    const int tx = t & 15;
    float F[4][4] = {};
    float G[4][4] = {};
#pragma unroll
    for (int k = 0; k < 32; ++k) {
        const float w = W4[k];
        const float4 ai = *reinterpret_cast<const float4*>(&FT[0][k][4 * ty]);
        const float4 bi = *reinterpret_cast<const float4*>(&FT[1][k][4 * ty]);
        const float4 aj = *reinterpret_cast<const float4*>(&FT[2][k][4 * tx]);
        const float4 bj = *reinterpret_cast<const float4*>(&FT[3][k][4 * tx]);
        const float av[4] = {ai.x, ai.y, ai.z, ai.w};
        const float bw[4] = {bi.x, bi.y, bi.z, bi.w};
        const float aw[4] = {aj.x, aj.y, aj.z, aj.w};
        const float bv[4] = {bj.x, bj.y, bj.z, bj.w};
#pragma unroll
        for (int a = 0; a < 4; ++a)
#pragma unroll
            for (int c = 0; c < 4; ++c) {
                F[a][c] = fmaf(fmaxf(av[a] + bv[c], 0.f), w, F[a][c]);
                G[a][c] = fmaf(fmaxf(aw[c] + bw[a], 0.f), w, G[a][c]);
            }
    }
    const float bb = *b4;
    float S[4][4];
#pragma unroll
    for (int a = 0; a < 4; ++a)
#pragma unroll
        for (int c = 0; c < 4; ++c)
            S[a][c] = 0.5f * (tanh_fast(F[a][c] + bb) + tanh_fast(G[a][c] + bb));
    float* outb = out + (size_t)b * (NROW * NROW);
    const int i0 = ti * 64 + 4 * ty;
    const int j0 = tj * 64 + 4 * tx;
#pragma unroll
    for (int a = 0; a < 4; ++a) {
        float4 v = make_float4(S[a][0], S[a][1], S[a][2], S[a][3]);
        *reinterpret_cast<float4*>(&outb[(size_t)(i0 + a) * NROW + j0]) = v;
    }
    if (ti != tj) {
#pragma unroll
        for (int c = 0; c < 4; ++c) {
            float4 v = make_float4(S[0][c], S[1][c], S[2][c], S[3][c]);
            *reinterpret_cast<float4*>(&outb[(size_t)(j0 + c) * NROW + i0]) = v;
        }
    }
}

extern "C" void kernel_launch(void* const* d_in, const int* in_sizes, int n_in,
                              void* d_out, int out_size, void* d_ws, size_t ws_size,
                              hipStream_t stream) {
    const float* emb  = (const float*)d_in[0];
    const float* temp = (const float*)d_in[1];
    const float* W1   = (const float*)d_in[2];
    const float* b1   = (const float*)d_in[3];
    const float* W2   = (const float*)d_in[4];
    const float* b2   = (const float*)d_in[5];
    const float* W3   = (const float*)d_in[6];
    const float* b3   = (const float*)d_in[7];
    const float* W4   = (const float*)d_in[8];
    const float* b4   = (const float*)d_in[9];
    float* out = (float*)d_out;

    const size_t need = (size_t)2 * NROWS_TOT * 32 * sizeof(float);
    if (ws_size >= need) {
        float* hiS  = (float*)d_ws;
        float* hjbS = hiS + (size_t)NROWS_TOT * 32;
        hipLaunchKernelGGL(k_feat, dim3(NPROD), dim3(256), 0, stream,
                           emb, temp, W1, b1, W2, b2, W3, b3, hiS, hjbS);
        hipLaunchKernelGGL(k_pair, dim3(NPAIRBLK), dim3(256), 0, stream,
                           hiS, hjbS, W4, b4, out);
    } else {
        hipLaunchKernelGGL(fused_fallback, dim3(BATCH * NTRI), dim3(256), 0, stream,
                           emb, temp, W1, b1, W2, b2, W3, b3, W4, b4, out);
    }
}

// Round 20
// 32.895 us; speedup vs baseline: 1.1808x; 1.1808x over previous
//
#include <hip/hip_runtime.h>
#include <math.h>

#define NROW 1024
#define BATCH 4
#define NT 16
#define NTRI 136             // 16*17/2
#define NPROD 1024
#define PROD_ROWS 4
#define NROWS_TOT 4096
#define NPAIRBLK (BATCH * NTRI * 4)  // 2176: 4 J-quarters per tile pair (r15 best)

__device__ __forceinline__ float tanh_fast(float x) {
    const float e = __expf(2.f * fabsf(x));
    const float r = 1.f - 2.f / (e + 1.f);
    return copysignf(r, x);
}

// ---------------------------------------------------------------------------
// Dispatch A: feature producer. 1024 blocks x 256 threads, 4 rows/block
// (4 blocks/CU, 16 waves/CU — 2x the latency hiding of the 512-block r15).
// ---------------------------------------------------------------------------
__global__ __launch_bounds__(256) void k_feat(
    const float* __restrict__ emb,   // [4096][128]
    const float* __restrict__ temp,  // [4096][64]
    const float* __restrict__ W1,    // [192][64]
    const float* __restrict__ b1,    // [64]
    const float* __restrict__ W2,    // [64][32]
    const float* __restrict__ b2,    // [32]
    const float* __restrict__ W3,    // [64][32]
    const float* __restrict__ b3,    // [32]
    float* __restrict__ hiS,         // [4096][32]
    float* __restrict__ hjbS)        // [4096][32]
{
    __shared__ __align__(16) float X[4 * 192];
    __shared__ __align__(16) float H[4 * 64];
    __shared__ __align__(16) float P[4 * 32];

    const int t = threadIdx.x;
    const int rowbase = blockIdx.x * PROD_ROWS;

    // stage X: 4 rows x 48 float4 = 192 float4 (threads 0..191)
    if (t < 192) {
        const int r = t / 48, c = t - (t / 48) * 48;
        float4 v;
        if (c < 32) v = reinterpret_cast<const float4*>(emb)[(size_t)(rowbase + r) * 32 + c];
        else        v = reinterpret_cast<const float4*>(temp)[(size_t)(rowbase + r) * 16 + (c - 32)];
        *reinterpret_cast<float4*>(&X[r * 192 + c * 4]) = v;
    }
    __syncthreads();

    // L1: [4x192]@[192x64]+b1 -> relu -> H (1 row/thread)
    {
        const int o = t & 63;
        const int r0 = t >> 6;  // 0..3
        float s0 = b1[o];
#pragma unroll 4
        for (int k4 = 0; k4 < 48; ++k4) {
            const float4 x0 = *reinterpret_cast<const float4*>(&X[r0 * 192 + k4 * 4]);
            const float w0 = W1[(k4 * 4 + 0) * 64 + o];
            const float w1 = W1[(k4 * 4 + 1) * 64 + o];
            const float w2 = W1[(k4 * 4 + 2) * 64 + o];
            const float w3 = W1[(k4 * 4 + 3) * 64 + o];
            s0 = fmaf(x0.w, w3, fmaf(x0.z, w2, fmaf(x0.y, w1, fmaf(x0.x, w0, s0))));
        }
        H[r0 * 64 + o] = fmaxf(s0, 0.f);
    }
    __syncthreads();

    // L2: [4x64]@[64x32]+b2 -> relu -> P (threads 0..127, 1 row-col each)
    if (t < 128) {
        const int o2 = t & 31;
        const int r4 = t >> 5;  // 0..3
        float s = b2[o2];
#pragma unroll 8
        for (int k = 0; k < 64; ++k) s += H[r4 * 64 + k] * W2[k * 32 + o2];
        P[r4 * 32 + o2] = fmaxf(s, 0.f);
    }
    __syncthreads();

    // L3: hi = P@W3[:32]; hjb = P@W3[32:]+b3 (threads 0..127)
    if (t < 128) {
        const int o2 = t & 31;
        const int r4 = t >> 5;
        float sa = 0.f, sb = b3[o2];
#pragma unroll 8
        for (int k = 0; k < 32; ++k) {
            const float p = P[r4 * 32 + k];
            sa += p * W3[k * 32 + o2];
            sb += p * W3[(32 + k) * 32 + o2];
        }
        hiS[(size_t)(rowbase + r4) * 32 + o2] = sa;
        hjbS[(size_t)(rowbase + r4) * 32 + o2] = sb;
    }
}

// ---------------------------------------------------------------------------
// Dispatch B: pairwise consumer — round-15 geometry VERBATIM (best: 31.7us).
// 2176 blocks x 256 threads, per-thread 4x1 both directions.
// ---------------------------------------------------------------------------
__global__ __launch_bounds__(256) void k_pair(
    const float* __restrict__ hiS,   // [4096][32]
    const float* __restrict__ hjbS,  // [4096][32]
    const float* __restrict__ W4,    // [32]
    const float* __restrict__ b4,    // [1]
    float* __restrict__ out)         // [4][1024][1024]
{
    __shared__ __align__(16) float AiT[32 * 68];  // hi  I rows, [k][r0..63]
    __shared__ __align__(16) float BiT[32 * 68];  // hjb I rows
    __shared__ __align__(16) float AjT[32 * 20];  // hi  J quarter, [k][r0..15]
    __shared__ __align__(16) float BjT[32 * 20];  // hjb J quarter

    const int t = threadIdx.x;
    const int bx = blockIdx.x;
    const int pb = bx >> 2;      // tile-pair index
    const int q = bx & 3;        // J quarter: cols [q*16, q*16+16)
    const int b = pb / NTRI;
    int tidx = pb % NTRI;
    int ti = 0;
    while (tidx >= NT - ti) { tidx -= NT - ti; ++ti; }
    const int tj = ti + tidx;

    const float* hiB  = hiS + (size_t)b * (NROW * 32);
    const float* hjbB = hjbS + (size_t)b * (NROW * 32);

    // ---- stage I tiles (full 64 rows), proven path ----
#pragma unroll
    for (int rep = 0; rep < 2; ++rep) {
        const int idx = t + rep * 256;  // 0..511
        const int r = idx >> 3, k4 = idx & 7;
        const float4 vhi = reinterpret_cast<const float4*>(hiB)[(ti * 64 + r) * 8 + k4];
        const float4 vhj = reinterpret_cast<const float4*>(hjbB)[(ti * 64 + r) * 8 + k4];
        AiT[(k4 * 4 + 0) * 68 + r] = vhi.x; AiT[(k4 * 4 + 1) * 68 + r] = vhi.y;
        AiT[(k4 * 4 + 2) * 68 + r] = vhi.z; AiT[(k4 * 4 + 3) * 68 + r] = vhi.w;
        BiT[(k4 * 4 + 0) * 68 + r] = vhj.x; BiT[(k4 * 4 + 1) * 68 + r] = vhj.y;
        BiT[(k4 * 4 + 2) * 68 + r] = vhj.z; BiT[(k4 * 4 + 3) * 68 + r] = vhj.w;
    }
    // ---- stage J quarter tiles (16 rows): threads 0..127 ----
    if (t < 128) {
        const int r = t >> 3, k4 = t & 7;  // r 0..15
        const int grow = tj * 64 + q * 16 + r;
        const float4 vhi = reinterpret_cast<const float4*>(hiB)[grow * 8 + k4];
        const float4 vhj = reinterpret_cast<const float4*>(hjbB)[grow * 8 + k4];
        AjT[(k4 * 4 + 0) * 20 + r] = vhi.x; AjT[(k4 * 4 + 1) * 20 + r] = vhi.y;
        AjT[(k4 * 4 + 2) * 20 + r] = vhi.z; AjT[(k4 * 4 + 3) * 20 + r] = vhi.w;
        BjT[(k4 * 4 + 0) * 20 + r] = vhj.x; BjT[(k4 * 4 + 1) * 20 + r] = vhj.y;
        BjT[(k4 * 4 + 2) * 20 + r] = vhj.z; BjT[(k4 * 4 + 3) * 20 + r] = vhj.w;
    }
    __syncthreads();

    const int ty = t >> 4;  // 0..15 -> 4 I-rows (i0..i0+3)
    const int tx = t & 15;  // 0..15 -> 1 J-col

    float F[4] = {};  // z(i0+a, j0)
    float G[4] = {};  // z(j0, i0+a)
#pragma unroll
    for (int k = 0; k < 32; ++k) {
        const float w = W4[k];
        const float4 ai = *reinterpret_cast<const float4*>(&AiT[k * 68 + 4 * ty]);  // hi  I
        const float4 bi = *reinterpret_cast<const float4*>(&BiT[k * 68 + 4 * ty]);  // hjb I
        const float aj = AjT[k * 20 + tx];  // hi  J
        const float bj = BjT[k * 20 + tx];  // hjb J
        const float av[4] = {ai.x, ai.y, ai.z, ai.w};
        const float bw[4] = {bi.x, bi.y, bi.z, bi.w};
#pragma unroll
        for (int a = 0; a < 4; ++a) {
            F[a] = fmaf(fmaxf(av[a] + bj, 0.f), w, F[a]);
            G[a] = fmaf(fmaxf(aj + bw[a], 0.f), w, G[a]);
        }
    }

    const float bb = *b4;
    float S[4];
#pragma unroll
    for (int a = 0; a < 4; ++a)
        S[a] = 0.5f * (tanh_fast(F[a] + bb) + tanh_fast(G[a] + bb));

    float* outb = out + (size_t)b * (NROW * NROW);
    const int i0 = ti * 64 + 4 * ty;
    const int j0 = tj * 64 + q * 16 + tx;
#pragma unroll
    for (int a = 0; a < 4; ++a)
        outb[(size_t)(i0 + a) * NROW + j0] = S[a];
    if (ti != tj) {
        float4 v = make_float4(S[0], S[1], S[2], S[3]);
        *reinterpret_cast<float4*>(&outb[(size_t)j0 * NROW + i0]) = v;
    }
}

// ---------------------------------------------------------------------------
// Fallback (ws too small): round-4 self-contained kernel, known-good @229us.
// ---------------------------------------------------------------------------
__global__ __launch_bounds__(256) void fused_fallback(
    const float* __restrict__ emb, const float* __restrict__ temp,
    const float* __restrict__ W1, const float* __restrict__ b1,
    const float* __restrict__ W2, const float* __restrict__ b2,
    const float* __restrict__ W3, const float* __restrict__ b3,
    const float* __restrict__ W4, const float* __restrict__ b4,
    float* __restrict__ out)
{
    __shared__ __align__(16) float FT[4][32][68];
    __shared__ __align__(16) float X[16][192];
    __shared__ __align__(16) float H[16][64];
    __shared__ __align__(16) float P[16][32];

    const int t = threadIdx.x;
    const int bx = blockIdx.x;
    const int b = bx / NTRI;
    int tidx = bx % NTRI;
    int ti = 0;
    while (tidx >= NT - ti) { tidx -= NT - ti; ++ti; }
    const int tj = ti + tidx;

    for (int ch = 0; ch < 8; ++ch) {
        const int tile = (ch < 4) ? ti : tj;
        const int sub = ch & 3;
        const int half = ch >> 2;
        const int rowbase = b * NROW + tile * 64 + sub * 16;
#pragma unroll
        for (int rep = 0; rep < 3; ++rep) {
            const int idx = t + rep * 256;
            const int r = idx / 48;
            const int c = idx - r * 48;
            float4 v;
            if (c < 32) v = reinterpret_cast<const float4*>(emb)[(size_t)(rowbase + r) * 32 + c];
            else        v = reinterpret_cast<const float4*>(temp)[(size_t)(rowbase + r) * 16 + (c - 32)];
            *reinterpret_cast<float4*>(&X[r][c * 4]) = v;
        }
        __syncthreads();
        {
            const int o = t & 63;
            const int r0 = t >> 6;
            float s0 = b1[o], s1 = s0, s2 = s0, s3 = s0;
#pragma unroll 4
            for (int k4 = 0; k4 < 48; ++k4) {
                const float4 x0 = *reinterpret_cast<const float4*>(&X[r0][k4 * 4]);
                const float4 x1 = *reinterpret_cast<const float4*>(&X[r0 + 4][k4 * 4]);
                const float4 x2 = *reinterpret_cast<const float4*>(&X[r0 + 8][k4 * 4]);
                const float4 x3 = *reinterpret_cast<const float4*>(&X[r0 + 12][k4 * 4]);
                const float w0 = W1[(k4 * 4 + 0) * 64 + o];
                const float w1 = W1[(k4 * 4 + 1) * 64 + o];
                const float w2 = W1[(k4 * 4 + 2) * 64 + o];
                const float w3 = W1[(k4 * 4 + 3) * 64 + o];
                s0 = fmaf(x0.w, w3, fmaf(x0.z, w2, fmaf(x0.y, w1, fmaf(x0.x, w0, s0))));
                s1 = fmaf(x1.w, w3, fmaf(x1.z, w2, fmaf(x1.y, w1, fmaf(x1.x, w0, s1))));
                s2 = fmaf(x2.w, w3, fmaf(x2.z, w2, fmaf(x2.y, w1, fmaf(x2.x, w0, s2))));
                s3 = fmaf(x3.w, w3, fmaf(x3.z, w2, fmaf(x3.y, w1, fmaf(x3.x, w0, s3))));
            }
            H[r0][o] = fmaxf(s0, 0.f);
            H[r0 + 4][o] = fmaxf(s1, 0.f);
            H[r0 + 8][o] = fmaxf(s2, 0.f);
            H[r0 + 12][o] = fmaxf(s3, 0.f);
        }
        __syncthreads();
        {
            const int o2 = t & 31;
            const int r8 = t >> 5;
#pragma unroll
            for (int rr = 0; rr < 2; ++rr) {
                const int r = r8 + rr * 8;
                float s = b2[o2];
#pragma unroll 8
                for (int k = 0; k < 64; ++k) s += H[r][k] * W2[k * 32 + o2];
                P[r][o2] = fmaxf(s, 0.f);
            }
        }
        __syncthreads();
        {
            const int o2 = t & 31;
            const int r8 = t >> 5;
#pragma unroll
            for (int rr = 0; rr < 2; ++rr) {
                const int r = r8 + rr * 8;
                float sa = 0.f, sb = b3[o2];
#pragma unroll 8
                for (int k = 0; k < 32; ++k) {
                    const float p = P[r][k];
                    sa += p * W3[k * 32 + o2];
                    sb += p * W3[(32 + k) * 32 + o2];
                }
                FT[half * 2 + 0][o2][sub * 16 + r] = sa;
                FT[half * 2 + 1][o2][sub * 16 + r] = sb;
            }
        }
        __syncthreads();
    }

    const int ty = t >> 4;
    const int tx = t & 15;
    float F[4][4] = {};
    float G[4][4] = {};
#pragma unroll
    for (int k = 0; k < 32; ++k) {
        const float w = W4[k];
        const float4 ai = *reinterpret_cast<const float4*>(&FT[0][k][4 * ty]);
        const float4 bi = *reinterpret_cast<const float4*>(&FT[1][k][4 * ty]);
        const float4 aj = *reinterpret_cast<const float4*>(&FT[2][k][4 * tx]);
        const float4 bj = *reinterpret_cast<const float4*>(&FT[3][k][4 * tx]);
        const float av[4] = {ai.x, ai.y, ai.z, ai.w};
        const float bw[4] = {bi.x, bi.y, bi.z, bi.w};
        const float aw[4] = {aj.x, aj.y, aj.z, aj.w};
        const float bv[4] = {bj.x, bj.y, bj.z, bj.w};
#pragma unroll
        for (int a = 0; a < 4; ++a)
#pragma unroll
            for (int c = 0; c < 4; ++c) {
                F[a][c] = fmaf(fmaxf(av[a] + bv[c], 0.f), w, F[a][c]);
                G[a][c] = fmaf(fmaxf(aw[c] + bw[a], 0.f), w, G[a][c]);
            }
    }
    const float bb = *b4;
    float S[4][4];
#pragma unroll
    for (int a = 0; a < 4; ++a)
#pragma unroll
        for (int c = 0; c < 4; ++c)
            S[a][c] = 0.5f * (tanh_fast(F[a][c] + bb) + tanh_fast(G[a][c] + bb));
    float* outb = out + (size_t)b * (NROW * NROW);
    const int i0 = ti * 64 + 4 * ty;
    const int j0 = tj * 64 + 4 * tx;
#pragma unroll
    for (int a = 0; a < 4; ++a) {
        float4 v = make_float4(S[a][0], S[a][1], S[a][2], S[a][3]);
        *reinterpret_cast<float4*>(&outb[(size_t)(i0 + a) * NROW + j0]) = v;
    }
    if (ti != tj) {
#pragma unroll
        for (int c = 0; c < 4; ++c) {
            float4 v = make_float4(S[0][c], S[1][c], S[2][c], S[3][c]);
            *reinterpret_cast<float4*>(&outb[(size_t)(j0 + c) * NROW + i0]) = v;
        }
    }
}

extern "C" void kernel_launch(void* const* d_in, const int* in_sizes, int n_in,
                              void* d_out, int out_size, void* d_ws, size_t ws_size,
                              hipStream_t stream) {
    const float* emb  = (const float*)d_in[0];
    const float* temp = (const float*)d_in[1];
    const float* W1   = (const float*)d_in[2];
    const float* b1   = (const float*)d_in[3];
    const float* W2   = (const float*)d_in[4];
    const float* b2   = (const float*)d_in[5];
    const float* W3   = (const float*)d_in[6];
    const float* b3   = (const float*)d_in[7];
    const float* W4   = (const float*)d_in[8];
    const float* b4   = (const float*)d_in[9];
    float* out = (float*)d_out;

    const size_t need = (size_t)2 * NROWS_TOT * 32 * sizeof(float);
    if (ws_size >= need) {
        float* hiS  = (float*)d_ws;
        float* hjbS = hiS + (size_t)NROWS_TOT * 32;
        hipLaunchKernelGGL(k_feat, dim3(NPROD), dim3(256), 0, stream,
                           emb, temp, W1, b1, W2, b2, W3, b3, hiS, hjbS);
        hipLaunchKernelGGL(k_pair, dim3(NPAIRBLK), dim3(256), 0, stream,
                           hiS, hjbS, W4, b4, out);
    } else {
        hipLaunchKernelGGL(fused_fallback, dim3(BATCH * NTRI), dim3(256), 0, stream,
                           emb, temp, W1, b1, W2, b2, W3, b3, W4, b4, out);
    }
}

// Round 21
// 31.538 us; speedup vs baseline: 1.2316x; 1.0430x over previous
//
#include <hip/hip_runtime.h>
#include <math.h>

#define NROW 1024
#define BATCH 4
#define NT 16
#define NTRI 136             // 16*17/2
#define NPROD 512
#define PROD_ROWS 8
#define NROWS_TOT 4096
#define NPAIRBLK (BATCH * NTRI * 4)  // 2176: 4 J-quarters per tile pair (r15 best)

__device__ __forceinline__ float tanh_fast(float x) {
    const float e = __expf(2.f * fabsf(x));
    const float r = 1.f - 2.f / (e + 1.f);
    return copysignf(r, x);
}

// ---------------------------------------------------------------------------
// Dispatch A: feature producer (round-15 best). 512 x 256, 8 rows/block.
// ---------------------------------------------------------------------------
__global__ __launch_bounds__(256) void k_feat(
    const float* __restrict__ emb,   // [4096][128]
    const float* __restrict__ temp,  // [4096][64]
    const float* __restrict__ W1,    // [192][64]
    const float* __restrict__ b1,    // [64]
    const float* __restrict__ W2,    // [64][32]
    const float* __restrict__ b2,    // [32]
    const float* __restrict__ W3,    // [64][32]
    const float* __restrict__ b3,    // [32]
    float* __restrict__ hiS,         // [4096][32]
    float* __restrict__ hjbS)        // [4096][32]
{
    __shared__ __align__(16) float X[8 * 192];
    __shared__ __align__(16) float H[8 * 64];
    __shared__ __align__(16) float P[8 * 32];

    const int t = threadIdx.x;
    const int rowbase = blockIdx.x * PROD_ROWS;

    {
        const int idx0 = t;            // 0..255
        const int r0s = idx0 / 48, c0 = idx0 - r0s * 48;
        float4 v;
        if (c0 < 32) v = reinterpret_cast<const float4*>(emb)[(size_t)(rowbase + r0s) * 32 + c0];
        else         v = reinterpret_cast<const float4*>(temp)[(size_t)(rowbase + r0s) * 16 + (c0 - 32)];
        *reinterpret_cast<float4*>(&X[r0s * 192 + c0 * 4]) = v;
        if (t < 128) {
            const int idx1 = t + 256;  // 256..383
            const int r1s = idx1 / 48, c1 = idx1 - r1s * 48;
            float4 v1;
            if (c1 < 32) v1 = reinterpret_cast<const float4*>(emb)[(size_t)(rowbase + r1s) * 32 + c1];
            else         v1 = reinterpret_cast<const float4*>(temp)[(size_t)(rowbase + r1s) * 16 + (c1 - 32)];
            *reinterpret_cast<float4*>(&X[r1s * 192 + c1 * 4]) = v1;
        }
    }
    __syncthreads();

    // L1: [8x192]@[192x64]+b1 -> relu -> H (2 independent rows/thread)
    {
        const int o = t & 63;
        const int r0 = t >> 6;  // 0..3 -> rows r0, r0+4
        float s0 = b1[o], s1 = s0;
#pragma unroll 4
        for (int k4 = 0; k4 < 48; ++k4) {
            const float4 x0 = *reinterpret_cast<const float4*>(&X[r0 * 192 + k4 * 4]);
            const float4 x1 = *reinterpret_cast<const float4*>(&X[(r0 + 4) * 192 + k4 * 4]);
            const float w0 = W1[(k4 * 4 + 0) * 64 + o];
            const float w1 = W1[(k4 * 4 + 1) * 64 + o];
            const float w2 = W1[(k4 * 4 + 2) * 64 + o];
            const float w3 = W1[(k4 * 4 + 3) * 64 + o];
            s0 = fmaf(x0.w, w3, fmaf(x0.z, w2, fmaf(x0.y, w1, fmaf(x0.x, w0, s0))));
            s1 = fmaf(x1.w, w3, fmaf(x1.z, w2, fmaf(x1.y, w1, fmaf(x1.x, w0, s1))));
        }
        H[r0 * 64 + o]       = fmaxf(s0, 0.f);
        H[(r0 + 4) * 64 + o] = fmaxf(s1, 0.f);
    }
    __syncthreads();

    // L2: [8x64]@[64x32]+b2 -> relu -> P (1 row/thread)
    {
        const int o2 = t & 31;
        const int r8 = t >> 5;  // 0..7
        float s = b2[o2];
#pragma unroll 8
        for (int k = 0; k < 64; ++k) s += H[r8 * 64 + k] * W2[k * 32 + o2];
        P[r8 * 32 + o2] = fmaxf(s, 0.f);
    }
    __syncthreads();

    // L3: hi = P@W3[:32]; hjb = P@W3[32:]+b3 (1 row/thread)
    {
        const int o2 = t & 31;
        const int r8 = t >> 5;
        float sa = 0.f, sb = b3[o2];
#pragma unroll 8
        for (int k = 0; k < 32; ++k) {
            const float p = P[r8 * 32 + k];
            sa += p * W3[k * 32 + o2];
            sb += p * W3[(32 + k) * 32 + o2];
        }
        hiS[(size_t)(rowbase + r8) * 32 + o2] = sa;
        hjbS[(size_t)(rowbase + r8) * 32 + o2] = sb;
    }
}

// ---------------------------------------------------------------------------
// Dispatch B: pairwise consumer — round-15 geometry VERBATIM (best: 31.7us).
// 2176 blocks x 256 threads, per-thread 4x1 both directions.
// ---------------------------------------------------------------------------
__global__ __launch_bounds__(256) void k_pair(
    const float* __restrict__ hiS,   // [4096][32]
    const float* __restrict__ hjbS,  // [4096][32]
    const float* __restrict__ W4,    // [32]
    const float* __restrict__ b4,    // [1]
    float* __restrict__ out)         // [4][1024][1024]
{
    __shared__ __align__(16) float AiT[32 * 68];  // hi  I rows, [k][r0..63]
    __shared__ __align__(16) float BiT[32 * 68];  // hjb I rows
    __shared__ __align__(16) float AjT[32 * 20];  // hi  J quarter, [k][r0..15]
    __shared__ __align__(16) float BjT[32 * 20];  // hjb J quarter

    const int t = threadIdx.x;
    const int bx = blockIdx.x;
    const int pb = bx >> 2;      // tile-pair index
    const int q = bx & 3;        // J quarter: cols [q*16, q*16+16)
    const int b = pb / NTRI;
    int tidx = pb % NTRI;
    int ti = 0;
    while (tidx >= NT - ti) { tidx -= NT - ti; ++ti; }
    const int tj = ti + tidx;

    const float* hiB  = hiS + (size_t)b * (NROW * 32);
    const float* hjbB = hjbS + (size_t)b * (NROW * 32);

    // ---- stage I tiles (full 64 rows), proven path ----
#pragma unroll
    for (int rep = 0; rep < 2; ++rep) {
        const int idx = t + rep * 256;  // 0..511
        const int r = idx >> 3, k4 = idx & 7;
        const float4 vhi = reinterpret_cast<const float4*>(hiB)[(ti * 64 + r) * 8 + k4];
        const float4 vhj = reinterpret_cast<const float4*>(hjbB)[(ti * 64 + r) * 8 + k4];
        AiT[(k4 * 4 + 0) * 68 + r] = vhi.x; AiT[(k4 * 4 + 1) * 68 + r] = vhi.y;
        AiT[(k4 * 4 + 2) * 68 + r] = vhi.z; AiT[(k4 * 4 + 3) * 68 + r] = vhi.w;
        BiT[(k4 * 4 + 0) * 68 + r] = vhj.x; BiT[(k4 * 4 + 1) * 68 + r] = vhj.y;
        BiT[(k4 * 4 + 2) * 68 + r] = vhj.z; BiT[(k4 * 4 + 3) * 68 + r] = vhj.w;
    }
    // ---- stage J quarter tiles (16 rows): threads 0..127 ----
    if (t < 128) {
        const int r = t >> 3, k4 = t & 7;  // r 0..15
        const int grow = tj * 64 + q * 16 + r;
        const float4 vhi = reinterpret_cast<const float4*>(hiB)[grow * 8 + k4];
        const float4 vhj = reinterpret_cast<const float4*>(hjbB)[grow * 8 + k4];
        AjT[(k4 * 4 + 0) * 20 + r] = vhi.x; AjT[(k4 * 4 + 1) * 20 + r] = vhi.y;
        AjT[(k4 * 4 + 2) * 20 + r] = vhi.z; AjT[(k4 * 4 + 3) * 20 + r] = vhi.w;
        BjT[(k4 * 4 + 0) * 20 + r] = vhj.x; BjT[(k4 * 4 + 1) * 20 + r] = vhj.y;
        BjT[(k4 * 4 + 2) * 20 + r] = vhj.z; BjT[(k4 * 4 + 3) * 20 + r] = vhj.w;
    }
    __syncthreads();

    const int ty = t >> 4;  // 0..15 -> 4 I-rows (i0..i0+3)
    const int tx = t & 15;  // 0..15 -> 1 J-col

    float F[4] = {};  // z(i0+a, j0)
    float G[4] = {};  // z(j0, i0+a)
#pragma unroll
    for (int k = 0; k < 32; ++k) {
        const float w = W4[k];
        const float4 ai = *reinterpret_cast<const float4*>(&AiT[k * 68 + 4 * ty]);  // hi  I
        const float4 bi = *reinterpret_cast<const float4*>(&BiT[k * 68 + 4 * ty]);  // hjb I
        const float aj = AjT[k * 20 + tx];  // hi  J
        const float bj = BjT[k * 20 + tx];  // hjb J
        const float av[4] = {ai.x, ai.y, ai.z, ai.w};
        const float bw[4] = {bi.x, bi.y, bi.z, bi.w};
#pragma unroll
        for (int a = 0; a < 4; ++a) {
            F[a] = fmaf(fmaxf(av[a] + bj, 0.f), w, F[a]);
            G[a] = fmaf(fmaxf(aj + bw[a], 0.f), w, G[a]);
        }
    }

    const float bb = *b4;
    float S[4];
#pragma unroll
    for (int a = 0; a < 4; ++a)
        S[a] = 0.5f * (tanh_fast(F[a] + bb) + tanh_fast(G[a] + bb));

    float* outb = out + (size_t)b * (NROW * NROW);
    const int i0 = ti * 64 + 4 * ty;
    const int j0 = tj * 64 + q * 16 + tx;
#pragma unroll
    for (int a = 0; a < 4; ++a)
        outb[(size_t)(i0 + a) * NROW + j0] = S[a];
    if (ti != tj) {
        float4 v = make_float4(S[0], S[1], S[2], S[3]);
        *reinterpret_cast<float4*>(&outb[(size_t)j0 * NROW + i0]) = v;
    }
}

// ---------------------------------------------------------------------------
// Fallback (ws too small): round-4 self-contained kernel, known-good @229us.
// ---------------------------------------------------------------------------
__global__ __launch_bounds__(256) void fused_fallback(
    const float* __restrict__ emb, const float* __restrict__ temp,
    const float* __restrict__ W1, const float* __restrict__ b1,
    const float* __restrict__ W2, const float* __restrict__ b2,
    const float* __restrict__ W3, const float* __restrict__ b3,
    const float* __restrict__ W4, const float* __restrict__ b4,
    float* __restrict__ out)
{
    __shared__ __align__(16) float FT[4][32][68];
    __shared__ __align__(16) float X[16][192];
    __shared__ __align__(16) float H[16][64];
    __shared__ __align__(16) float P[16][32];

    const int t = threadIdx.x;
    const int bx = blockIdx.x;
    const int b = bx / NTRI;
    int tidx = bx % NTRI;
    int ti = 0;
    while (tidx >= NT - ti) { tidx -= NT - ti; ++ti; }
    const int tj = ti + tidx;

    for (int ch = 0; ch < 8; ++ch) {
        const int tile = (ch < 4) ? ti : tj;
        const int sub = ch & 3;
        const int half = ch >> 2;
        const int rowbase = b * NROW + tile * 64 + sub * 16;
#pragma unroll
        for (int rep = 0; rep < 3; ++rep) {
            const int idx = t + rep * 256;
            const int r = idx / 48;
            const int c = idx - r * 48;
            float4 v;
            if (c < 32) v = reinterpret_cast<const float4*>(emb)[(size_t)(rowbase + r) * 32 + c];
            else        v = reinterpret_cast<const float4*>(temp)[(size_t)(rowbase + r) * 16 + (c - 32)];
            *reinterpret_cast<float4*>(&X[r][c * 4]) = v;
        }
        __syncthreads();
        {
            const int o = t & 63;
            const int r0 = t >> 6;
            float s0 = b1[o], s1 = s0, s2 = s0, s3 = s0;
#pragma unroll 4
            for (int k4 = 0; k4 < 48; ++k4) {
                const float4 x0 = *reinterpret_cast<const float4*>(&X[r0][k4 * 4]);
                const float4 x1 = *reinterpret_cast<const float4*>(&X[r0 + 4][k4 * 4]);
                const float4 x2 = *reinterpret_cast<const float4*>(&X[r0 + 8][k4 * 4]);
                const float4 x3 = *reinterpret_cast<const float4*>(&X[r0 + 12][k4 * 4]);
                const float w0 = W1[(k4 * 4 + 0) * 64 + o];
                const float w1 = W1[(k4 * 4 + 1) * 64 + o];
                const float w2 = W1[(k4 * 4 + 2) * 64 + o];
                const float w3 = W1[(k4 * 4 + 3) * 64 + o];
                s0 = fmaf(x0.w, w3, fmaf(x0.z, w2, fmaf(x0.y, w1, fmaf(x0.x, w0, s0))));
                s1 = fmaf(x1.w, w3, fmaf(x1.z, w2, fmaf(x1.y, w1, fmaf(x1.x, w0, s1))));
                s2 = fmaf(x2.w, w3, fmaf(x2.z, w2, fmaf(x2.y, w1, fmaf(x2.x, w0, s2))));
                s3 = fmaf(x3.w, w3, fmaf(x3.z, w2, fmaf(x3.y, w1, fmaf(x3.x, w0, s3))));
            }
            H[r0][o] = fmaxf(s0, 0.f);
            H[r0 + 4][o] = fmaxf(s1, 0.f);
            H[r0 + 8][o] = fmaxf(s2, 0.f);
            H[r0 + 12][o] = fmaxf(s3, 0.f);
        }
        __syncthreads();
        {
            const int o2 = t & 31;
            const int r8 = t >> 5;
#pragma unroll
            for (int rr = 0; rr < 2; ++rr) {
                const int r = r8 + rr * 8;
                float s = b2[o2];
#pragma unroll 8
                for (int k = 0; k < 64; ++k) s += H[r][k] * W2[k * 32 + o2];
                P[r][o2] = fmaxf(s, 0.f);
            }
        }
        __syncthreads();
        {
            const int o2 = t & 31;
            const int r8 = t >> 5;
#pragma unroll
            for (int rr = 0; rr < 2; ++rr) {
                const int r = r8 + rr * 8;
                float sa = 0.f, sb = b3[o2];
#pragma unroll 8
                for (int k = 0; k < 32; ++k) {
                    const float p = P[r][k];
                    sa += p * W3[k * 32 + o2];
                    sb += p * W3[(32 + k) * 32 + o2];
                }
                FT[half * 2 + 0][o2][sub * 16 + r] = sa;
                FT[half * 2 + 1][o2][sub * 16 + r] = sb;
            }
        }
        __syncthreads();
    }

    const int ty = t >> 4;
    const int tx = t & 15;
    float F[4][4] = {};
    float G[4][4] = {};
#pragma unroll
    for (int k = 0; k < 32; ++k) {
        const float w = W4[k];
        const float4 ai = *reinterpret_cast<const float4*>(&FT[0][k][4 * ty]);
        const float4 bi = *reinterpret_cast<const float4*>(&FT[1][k][4 * ty]);
        const float4 aj = *reinterpret_cast<const float4*>(&FT[2][k][4 * tx]);
        const float4 bj = *reinterpret_cast<const float4*>(&FT[3][k][4 * tx]);
        const float av[4] = {ai.x, ai.y, ai.z, ai.w};
        const float bw[4] = {bi.x, bi.y, bi.z, bi.w};
        const float aw[4] = {aj.x, aj.y, aj.z, aj.w};
        const float bv[4] = {bj.x, bj.y, bj.z, bj.w};
#pragma unroll
        for (int a = 0; a < 4; ++a)
#pragma unroll
            for (int c = 0; c < 4; ++c) {
                F[a][c] = fmaf(fmaxf(av[a] + bv[c], 0.f), w, F[a][c]);
                G[a][c] = fmaf(fmaxf(aw[c] + bw[a], 0.f), w, G[a][c]);
            }
    }
    const float bb = *b4;
    float S[4][4];
#pragma unroll
    for (int a = 0; a < 4; ++a)
#pragma unroll
        for (int c = 0; c < 4; ++c)
            S[a][c] = 0.5f * (tanh_fast(F[a][c] + bb) + tanh_fast(G[a][c] + bb));
    float* outb = out + (size_t)b * (NROW * NROW);
    const int i0 = ti * 64 + 4 * ty;
    const int j0 = tj * 64 + 4 * tx;
#pragma unroll
    for (int a = 0; a < 4; ++a) {
        float4 v = make_float4(S[a][0], S[a][1], S[a][2], S[a][3]);
        *reinterpret_cast<float4*>(&outb[(size_t)(i0 + a) * NROW + j0]) = v;
    }
    if (ti != tj) {
#pragma unroll
        for (int c = 0; c < 4; ++c) {
            float4 v = make_float4(S[0][c], S[1][c], S[2][c], S[3][c]);
            *reinterpret_cast<float4*>(&outb[(size_t)(j0 + c) * NROW + i0]) = v;
        }
    }
}

extern "C" void kernel_launch(void* const* d_in, const int* in_sizes, int n_in,
                              void* d_out, int out_size, void* d_ws, size_t ws_size,
                              hipStream_t stream) {
    const float* emb  = (const float*)d_in[0];
    const float* temp = (const float*)d_in[1];
    const float* W1   = (const float*)d_in[2];
    const float* b1   = (const float*)d_in[3];
    const float* W2   = (const float*)d_in[4];
    const float* b2   = (const float*)d_in[5];
    const float* W3   = (const float*)d_in[6];
    const float* b3   = (const float*)d_in[7];
    const float* W4   = (const float*)d_in[8];
    const float* b4   = (const float*)d_in[9];
    float* out = (float*)d_out;

    const size_t need = (size_t)2 * NROWS_TOT * 32 * sizeof(float);
    if (ws_size >= need) {
        float* hiS  = (float*)d_ws;
        float* hjbS = hiS + (size_t)NROWS_TOT * 32;
        hipLaunchKernelGGL(k_feat, dim3(NPROD), dim3(256), 0, stream,
                           emb, temp, W1, b1, W2, b2, W3, b3, hiS, hjbS);
        hipLaunchKernelGGL(k_pair, dim3(NPAIRBLK), dim3(256), 0, stream,
                           hiS, hjbS, W4, b4, out);
    } else {
        hipLaunchKernelGGL(fused_fallback, dim3(BATCH * NTRI), dim3(256), 0, stream,
                           emb, temp, W1, b1, W2, b2, W3, b3, W4, b4, out);
    }
}